// Round 18
// baseline (407.237 us; speedup 1.0000x reference)
//
#include <hip/hip_runtime.h>
#include <hip/hip_fp16.h>

#define NPART 22
#define NDEG  21
#define NEDGE 462
#define HID   64
#define NLAYERS 4
#define NSTRIPB 29      // 16-edge strips per batch
#define NPAIRB  15      // strip pairs per batch (2 strips/wave)
#define MW2S  72        // u16 row stride of wave-private m tile

typedef _Float16 f16x8 __attribute__((ext_vector_type(8)));
typedef __attribute__((ext_vector_type(4))) float f32x4;
typedef __attribute__((ext_vector_type(4))) unsigned int u32x4;

__device__ __forceinline__ float silu_f(float v) {
    return __fdividef(v, 1.0f + __expf(-v));
}
__device__ __forceinline__ unsigned short hfu(float v) {
    return __half_as_ushort(__float2half(v));
}

// ---- edge-weight B-fragments: W2 / Wc1 per layer (f16) ----
__global__ void prep_wfrag(const float* __restrict__ edge_w2,
                           const float* __restrict__ coord_w1,
                           unsigned* __restrict__ wfrag)
{
    const int m = blockIdx.x;      // 0..7: L*2 + {0:W2, 1:Wc1}
    const int l = threadIdx.x;
    const int L = m >> 1;
    const float* W = (m & 1) ? (coord_w1 + L*HID*HID) : (edge_w2 + L*HID*HID);
    const int kg = l >> 4, j0 = l & 15;
    u32x4* ws4 = (u32x4*)wfrag;
    #pragma unroll
    for (int nt = 0; nt < 4; ++nt) {
        #pragma unroll
        for (int c = 0; c < 2; ++c) {
            u32x4 p;
            #pragma unroll
            for (int pi = 0; pi < 4; ++pi) {
                int k = c*32 + kg*8 + 2*pi;
                float v0 = W[k*HID + nt*16 + j0];
                float v1 = W[(k+1)*HID + nt*16 + j0];
                p[pi] = (unsigned)hfu(v0) | ((unsigned)hfu(v1) << 16);
            }
            ws4[m*512 + (nt*2 + c)*64 + l] = p;
        }
    }
}

// ---- node-weight B-fragments: wn1(K=128), wn2, we1r, we1c (f16) ----
__global__ void prep_nfrag(const float* __restrict__ node_w1,
                           const float* __restrict__ node_w2,
                           const float* __restrict__ edge_w1,
                           unsigned* __restrict__ nfrag)
{
    const int b = blockIdx.x;            // 0..11: L = b>>2, mat = b&3
    const int L = b >> 2, mat = b & 3;
    const int l = threadIdx.x;
    const int kg = l >> 4, j0 = l & 15;
    u32x4* nf = (u32x4*)nfrag + (size_t)L*40*64;
    const float* W; int nc, base;
    if      (mat == 0) { W = node_w1 + L*2*HID*HID;            nc = 4; base = 0;  }
    else if (mat == 1) { W = node_w2 + L*HID*HID;              nc = 2; base = 16; }
    else if (mat == 2) { W = edge_w1 + (L+1)*130*HID;          nc = 2; base = 24; }
    else               { W = edge_w1 + (L+1)*130*HID + 64*HID; nc = 2; base = 32; }
    for (int nt = 0; nt < 4; ++nt) {
        for (int c = 0; c < nc; ++c) {
            u32x4 p;
            #pragma unroll
            for (int pi = 0; pi < 4; ++pi) {
                int k = c*32 + kg*8 + 2*pi;
                float v0 = W[k*HID + nt*16 + j0];
                float v1 = W[(k+1)*HID + nt*16 + j0];
                p[pi] = (unsigned)hfu(v0) | ((unsigned)hfu(v1) << 16);
            }
            nf[(size_t)(base + nt*nc + c)*64 + l] = p;
        }
    }
}

// ---- static per-edge attribute: eav = |x0_a - x0_b|^2 ----
__global__ void k_eav(const float* __restrict__ xs, float* __restrict__ eavg)
{
    __shared__ float xsh[68];
    const int b = blockIdx.x, t = threadIdx.x;
    if (t < 66) xsh[t] = xs[b*66 + t];
    __syncthreads();
    for (int e = t; e < NEDGE; e += 256) {
        int a = e / NDEG, r = e - a*NDEG;
        int bb = r + (r >= a ? 1 : 0);
        float d0 = xsh[a*3+0] - xsh[bb*3+0];
        float d1 = xsh[a*3+1] - xsh[bb*3+1];
        float d2 = xsh[a*3+2] - xsh[bb*3+2];
        eavg[(size_t)b*464 + e] = d0*d0 + d1*d1 + d2*d2;
    }
}

// ---- init: h embedding, x copy, layer-0 Hr/Hc ----
__global__ __launch_bounds__(256, 4)
void k_init(const float* __restrict__ t_in, const float* __restrict__ xs,
            const float* __restrict__ h_init,
            const float* __restrict__ emb_w, const float* __restrict__ emb_b,
            const float* __restrict__ edge_w1, const float* __restrict__ edge_b1,
            float* __restrict__ xw, float* __restrict__ hw,
            float* __restrict__ Hrw, float* __restrict__ Hcw, int NT)
{
    __shared__ __align__(16) float hbuf[4][68];
    const int w = threadIdx.x >> 6, l = threadIdx.x & 63;
    const int n = blockIdx.x*4 + w;
    if (n >= NT) return;
    const int bidx = n / NPART, p = n - bidx*NPART;
    float hv = emb_b[l] + t_in[bidx]*emb_w[8*HID + l];
    #pragma unroll
    for (int k = 0; k < 8; ++k) hv += h_init[p*8 + k]*emb_w[k*HID + l];
    hw[(size_t)n*HID + l] = hv;
    hbuf[w][l] = hv;
    float accr = edge_b1[l], accc = 0.f;
    #pragma unroll 4
    for (int k = 0; k < HID; ++k) {
        float hk = hbuf[w][k];
        accr += hk*edge_w1[k*HID + l];
        accc += hk*edge_w1[(HID + k)*HID + l];
    }
    Hrw[(size_t)n*HID + l] = accr;
    Hcw[(size_t)n*HID + l] = accc;
    if (l < 3) xw[n*3 + l] = xs[n*3 + l];
}

// ---- phase A: TWO 16-edge strips per wave; f16 MFMA; no barriers/atomics ----
__global__ __launch_bounds__(256, 4)
void k_edgeA(const float* __restrict__ edge_w1v,   // vrad base; vea = +64
             const float* __restrict__ edge_b2L,
             const float* __restrict__ coord_b1L,
             const float* __restrict__ coord_w2L,
             const unsigned* __restrict__ wfrag,
             const float* __restrict__ eavg,
             const float* __restrict__ xw,
             const float* __restrict__ Hrw,
             const float* __restrict__ Hcw,
             float* __restrict__ aggpart,
             float* __restrict__ scalg,
             int npairs, int Lmat)
{
    __shared__ __align__(16) unsigned short mwall[4][16*MW2S];
    __shared__ __align__(16) float xst[4][68];

    const int tid = threadIdx.x, l = tid & 63, w = tid >> 6;
    const int kg = l >> 4, j0 = l & 15;

    const int pid = blockIdx.x*4 + w;
    if (pid >= npairs) return;
    const int batch = pid / NPAIRB, t = pid - batch*NPAIRB;

    {   // stage current x for this batch (once per pair)
        const int base = batch*66;
        xst[w][l] = xw[base + ((l < 66) ? l : 0)];
        if (l < 2) xst[w][64 + l] = xw[base + 64 + l];
    }

    // pair-invariant: B-fragments (both GEMMs) + bias/coord vectors
    const u32x4* ws4 = (const u32x4*)wfrag;
    const u32x4* wb1 = ws4 + (size_t)(Lmat*2    )*512 + l;
    const u32x4* wb2 = ws4 + (size_t)(Lmat*2 + 1)*512 + l;
    f16x8 BW1[4][2], B2[4][2];
    #pragma unroll
    for (int nt = 0; nt < 4; ++nt) {
        BW1[nt][0] = __builtin_bit_cast(f16x8, wb1[(nt*2 + 0)*64]);
        BW1[nt][1] = __builtin_bit_cast(f16x8, wb1[(nt*2 + 1)*64]);
        B2[nt][0]  = __builtin_bit_cast(f16x8, wb2[(nt*2 + 0)*64]);
        B2[nt][1]  = __builtin_bit_cast(f16x8, wb2[(nt*2 + 1)*64]);
    }
    float bv[4], cb[4], cw[4];
    #pragma unroll
    for (int nt = 0; nt < 4; ++nt) {
        bv[nt] = edge_b2L[nt*16 + j0];
        cb[nt] = coord_b1L[nt*16 + j0];
        cw[nt] = coord_w2L[nt*16 + j0];
    }

    unsigned short* mw = mwall[w];

    for (int half = 0; half < 2; ++half) {
        const int s = 2*t + half;
        if (s >= NSTRIPB) break;
        const int e0 = s*16;
        const int ecnt = (NEDGE - e0 < 16) ? (NEDGE - e0) : 16;
        const int n0 = e0 / NDEG;

        int eg = e0 + j0; if (eg >= NEDGE) eg = NEDGE - 1;
        const int a  = eg / NDEG;
        const int r  = eg - a*NDEG;
        const int bb = r + (r >= a ? 1 : 0);
        float d0 = xst[w][a*3+0] - xst[w][bb*3+0];
        float d1 = xst[w][a*3+1] - xst[w][bb*3+1];
        float d2 = xst[w][a*3+2] - xst[w][bb*3+2];
        float rad = d0*d0 + d1*d1 + d2*d2;
        float eav = eavg[(size_t)batch*464 + eg];

        // m1 A-fragments (f16, straight build)
        f16x8 A1[2];
        {
            const float* hrp = Hrw + (size_t)(batch*NPART + a)*HID;
            const float* hcp = Hcw + (size_t)(batch*NPART + bb)*HID;
            #pragma unroll
            for (int c = 0; c < 2; ++c) {
                const int k0 = c*32 + kg*8;
                float4 ra = *(const float4*)(hrp + k0);
                float4 rb = *(const float4*)(hrp + k0 + 4);
                float4 ca = *(const float4*)(hcp + k0);
                float4 cb4 = *(const float4*)(hcp + k0 + 4);
                float4 va = *(const float4*)(edge_w1v + k0);
                float4 vb = *(const float4*)(edge_w1v + k0 + 4);
                float4 ua = *(const float4*)(edge_w1v + 64 + k0);
                float4 ub = *(const float4*)(edge_w1v + 64 + k0 + 4);
                f16x8 A;
                A[0] = (_Float16)silu_f(ra.x + ca.x + rad*va.x + eav*ua.x);
                A[1] = (_Float16)silu_f(ra.y + ca.y + rad*va.y + eav*ua.y);
                A[2] = (_Float16)silu_f(ra.z + ca.z + rad*va.z + eav*ua.z);
                A[3] = (_Float16)silu_f(ra.w + ca.w + rad*va.w + eav*ua.w);
                A[4] = (_Float16)silu_f(rb.x + cb4.x + rad*vb.x + eav*ub.x);
                A[5] = (_Float16)silu_f(rb.y + cb4.y + rad*vb.y + eav*ub.y);
                A[6] = (_Float16)silu_f(rb.z + cb4.z + rad*vb.z + eav*ub.z);
                A[7] = (_Float16)silu_f(rb.w + cb4.w + rad*vb.w + eav*ub.w);
                A1[c] = A;
            }
        }

        // GEMM1: m = m1 @ W2
        f32x4 acc[4];
        #pragma unroll
        for (int nt = 0; nt < 4; ++nt) {
            f32x4 z = {0.f, 0.f, 0.f, 0.f};
            z = __builtin_amdgcn_mfma_f32_16x16x32_f16(A1[0], BW1[nt][0], z, 0, 0, 0);
            z = __builtin_amdgcn_mfma_f32_16x16x32_f16(A1[1], BW1[nt][1], z, 0, 0, 0);
            acc[nt] = z;
        }

        // epilogue 1: silu+bias (emask-folded), f16 tile store, partials pS/pT
        int sel[4], emask[4];
        #pragma unroll
        for (int r2 = 0; r2 < 4; ++r2) {
            int e2 = kg*4 + r2;
            int eg2 = e0 + e2; if (eg2 >= NEDGE) eg2 = NEDGE - 1;
            sel[r2] = (eg2 / NDEG == n0);
            emask[r2] = (e2 < ecnt);
        }
        float pS[4] = {0.f,0.f,0.f,0.f}, pT[4] = {0.f,0.f,0.f,0.f};
        #pragma unroll
        for (int nt = 0; nt < 4; ++nt) {
            int j = nt*16 + j0;
            #pragma unroll
            for (int r2 = 0; r2 < 4; ++r2) {
                float mv = emask[r2] ? silu_f(acc[nt][r2] + bv[nt]) : 0.f;
                mw[(kg*4 + r2)*MW2S + j] = hfu(mv);
                pT[nt] += mv;
                pS[nt] += sel[r2] ? mv : 0.f;
            }
        }
        #pragma unroll
        for (int nt = 0; nt < 4; ++nt) {
            pS[nt] += __shfl_xor(pS[nt], 16);
            pS[nt] += __shfl_xor(pS[nt], 32);
            pT[nt] += __shfl_xor(pT[nt], 16);
            pT[nt] += __shfl_xor(pT[nt], 32);
        }
        {
            float* apb = aggpart + (size_t)(batch*NSTRIPB + s)*128;
            if (kg == 0) {
                #pragma unroll
                for (int nt = 0; nt < 4; ++nt) apb[nt*16 + j0] = pS[nt];
            } else if (kg == 1) {
                #pragma unroll
                for (int nt = 0; nt < 4; ++nt) apb[64 + nt*16 + j0] = pT[nt] - pS[nt];
            }
        }

        // GEMM2 A-fragments: direct b128 reads from f16 tile
        f16x8 A2[2];
        {
            const unsigned short* arp = mw + j0*MW2S;
            A2[0] = *(const f16x8*)(arp + kg*8);
            A2[1] = *(const f16x8*)(arp + 32 + kg*8);
        }

        // GEMM2: c1 = m @ Wc1
        f32x4 acc2[4];
        #pragma unroll
        for (int nt = 0; nt < 4; ++nt) {
            f32x4 z = {0.f, 0.f, 0.f, 0.f};
            z = __builtin_amdgcn_mfma_f32_16x16x32_f16(A2[0], B2[nt][0], z, 0, 0, 0);
            z = __builtin_amdgcn_mfma_f32_16x16x32_f16(A2[1], B2[nt][1], z, 0, 0, 0);
            acc2[nt] = z;
        }

        // epilogue 2: scal reduce over j0 lanes, store per edge
        float pr[4] = {0.f,0.f,0.f,0.f};
        #pragma unroll
        for (int nt = 0; nt < 4; ++nt) {
            #pragma unroll
            for (int r2 = 0; r2 < 4; ++r2)
                pr[r2] += silu_f(acc2[nt][r2] + cb[nt]) * cw[nt];
        }
        #pragma unroll
        for (int off = 8; off > 0; off >>= 1) {
            #pragma unroll
            for (int r2 = 0; r2 < 4; ++r2)
                pr[r2] += __shfl_xor(pr[r2], off);
        }
        if (j0 == 0) {
            #pragma unroll
            for (int r2 = 0; r2 < 4; ++r2) {
                int e2 = kg*4 + r2;
                if (e2 < ecnt) scalg[(size_t)batch*464 + e0 + e2] = pr[r2];
            }
        }
    }
}

// ---- fused: dx+x update (blocks < gD) | node MFMA phase (blocks >= gD) ----
__global__ __launch_bounds__(256, 2)
void k_dxnode(const float* __restrict__ scalg, float* __restrict__ xw, int NB, int gD,
              const unsigned* __restrict__ nfragL,
              const float* __restrict__ nb1p, const float* __restrict__ nb2p,
              const float* __restrict__ eb1p,
              const float* __restrict__ aggpart,
              float* __restrict__ hw,
              float* __restrict__ Hrw, float* __restrict__ Hcw,
              int NT, int nstripN)
{
    __shared__ __align__(16) float hT[4][16][68];
    __shared__ __align__(16) float hnT[4][16][68];
    __shared__ float xstd[4][68], dxd[4][68];
    const int tid = threadIdx.x, l = tid & 63, w = tid >> 6;
    const int kg = l >> 4, j0 = l & 15;

    if (blockIdx.x < (unsigned)gD) {
        const int batch = blockIdx.x*4 + w;
        if (batch >= NB) return;
        xstd[w][l] = xw[batch*66 + ((l < 66) ? l : 0)];
        if (l < 2) xstd[w][64 + l] = xw[batch*66 + 64 + l];
        dxd[w][l] = 0.f;
        if (l < 4) dxd[w][64 + l] = 0.f;
        for (int e = l; e < NEDGE; e += 64) {
            int a = e / NDEG, r = e - a*NDEG;
            int bb = r + (r >= a ? 1 : 0);
            float d0 = xstd[w][a*3+0] - xstd[w][bb*3+0];
            float d1 = xstd[w][a*3+1] - xstd[w][bb*3+1];
            float d2 = xstd[w][a*3+2] - xstd[w][bb*3+2];
            float inv = rsqrtf(d0*d0 + d1*d1 + d2*d2 + 1e-8f);
            float sc = scalg[(size_t)batch*464 + e] * inv;
            atomicAdd(&dxd[w][a*3+0], d0*sc);
            atomicAdd(&dxd[w][a*3+1], d1*sc);
            atomicAdd(&dxd[w][a*3+2], d2*sc);
        }
        xw[batch*66 + ((l < 66) ? l : 0)] = xstd[w][l] + dxd[w][l];
        if (l < 2) xw[batch*66 + 64 + l] = xstd[w][64 + l] + dxd[w][64 + l];
        return;
    }

    const int sid = (blockIdx.x - gD)*4 + w;
    if (sid >= nstripN) return;

    {
        int row = l >> 2, cc = (l & 3) << 4;
        int nd = sid*16 + row; if (nd >= NT) nd = NT - 1;
        const float* src = hw + (size_t)nd*HID + cc;
        *(float4*)&hT[w][row][cc]      = *(const float4*)(src);
        *(float4*)&hT[w][row][cc + 4]  = *(const float4*)(src + 4);
        *(float4*)&hT[w][row][cc + 8]  = *(const float4*)(src + 8);
        *(float4*)&hT[w][row][cc + 12] = *(const float4*)(src + 12);
    }

    const int ndl  = sid*16 + j0;
    const int ndc  = (ndl < NT) ? ndl : NT - 1;
    const int bidx = ndc / NPART, p = ndc - bidx*NPART;

    f16x8 A1[4];
    #pragma unroll
    for (int c = 0; c < 2; ++c) {
        f16x8 A;
        #pragma unroll
        for (int i = 0; i < 8; ++i) A[i] = (_Float16)hT[w][j0][c*32 + kg*8 + i];
        A1[c] = A;
    }
    {
        const int smin = (NDEG*p) >> 4;
        const int smax = (NDEG*p + 20) >> 4;
        #pragma unroll
        for (int c = 2; c < 4; ++c) {
            const int k0a = (c - 2)*32 + kg*8;
            float tv[8] = {0.f,0.f,0.f,0.f,0.f,0.f,0.f,0.f};
            for (int s = smin; s <= smax; ++s) {
                int slot = (p == (s*16)/NDEG) ? 0 : 1;
                const float* ap = aggpart + (size_t)(bidx*NSTRIPB + s)*128 + slot*64 + k0a;
                float4 qa = *(const float4*)ap;
                float4 qb = *(const float4*)(ap + 4);
                tv[0] += qa.x; tv[1] += qa.y; tv[2] += qa.z; tv[3] += qa.w;
                tv[4] += qb.x; tv[5] += qb.y; tv[6] += qb.z; tv[7] += qb.w;
            }
            f16x8 A;
            #pragma unroll
            for (int i = 0; i < 8; ++i) A[i] = (_Float16)tv[i];
            A1[c] = A;
        }
    }

    const u32x4* nf = (const u32x4*)nfragL;
    #define NBF(idx) __builtin_bit_cast(f16x8, nf[(size_t)(idx)*64 + l])

    f32x4 acc1[4];
    #pragma unroll
    for (int nt = 0; nt < 4; ++nt) {
        f32x4 z = {0.f, 0.f, 0.f, 0.f};
        #pragma unroll
        for (int c = 0; c < 4; ++c)
            z = __builtin_amdgcn_mfma_f32_16x16x32_f16(A1[c], NBF(nt*4 + c), z, 0, 0, 0);
        acc1[nt] = z;
    }
    #pragma unroll
    for (int nt = 0; nt < 4; ++nt) {
        float bv = nb1p[nt*16 + j0];
        #pragma unroll
        for (int r2 = 0; r2 < 4; ++r2)
            hnT[w][kg*4 + r2][nt*16 + j0] = silu_f(acc1[nt][r2] + bv);
    }

    f16x8 A2[2];
    #pragma unroll
    for (int c = 0; c < 2; ++c) {
        f16x8 A;
        #pragma unroll
        for (int i = 0; i < 8; ++i) A[i] = (_Float16)hnT[w][j0][c*32 + kg*8 + i];
        A2[c] = A;
    }
    f32x4 acc2[4];
    #pragma unroll
    for (int nt = 0; nt < 4; ++nt) {
        f32x4 z = {0.f, 0.f, 0.f, 0.f};
        #pragma unroll
        for (int c = 0; c < 2; ++c)
            z = __builtin_amdgcn_mfma_f32_16x16x32_f16(A2[c], NBF(16 + nt*2 + c), z, 0, 0, 0);
        acc2[nt] = z;
    }
    #pragma unroll
    for (int nt = 0; nt < 4; ++nt) {
        float bv = nb2p[nt*16 + j0];
        #pragma unroll
        for (int r2 = 0; r2 < 4; ++r2) {
            int row = kg*4 + r2, col = nt*16 + j0;
            float hv = hT[w][row][col] + acc2[nt][r2] + bv;
            hnT[w][row][col] = hv;
            int nd = sid*16 + row;
            if (nd < NT) hw[(size_t)nd*HID + col] = hv;
        }
    }

    f16x8 A3[2];
    #pragma unroll
    for (int c = 0; c < 2; ++c) {
        f16x8 A;
        #pragma unroll
        for (int i = 0; i < 8; ++i) A[i] = (_Float16)hnT[w][j0][c*32 + kg*8 + i];
        A3[c] = A;
    }
    f32x4 accR[4], accC[4];
    #pragma unroll
    for (int nt = 0; nt < 4; ++nt) {
        f32x4 zr = {0.f,0.f,0.f,0.f}, zc = {0.f,0.f,0.f,0.f};
        #pragma unroll
        for (int c = 0; c < 2; ++c) {
            zr = __builtin_amdgcn_mfma_f32_16x16x32_f16(A3[c], NBF(24 + nt*2 + c), zr, 0, 0, 0);
            zc = __builtin_amdgcn_mfma_f32_16x16x32_f16(A3[c], NBF(32 + nt*2 + c), zc, 0, 0, 0);
        }
        accR[nt] = zr; accC[nt] = zc;
    }
    #pragma unroll
    for (int nt = 0; nt < 4; ++nt) {
        float bv = eb1p[nt*16 + j0];
        #pragma unroll
        for (int r2 = 0; r2 < 4; ++r2) {
            int row = kg*4 + r2, col = nt*16 + j0;
            int nd = sid*16 + row;
            if (nd < NT) {
                Hrw[(size_t)nd*HID + col] = accR[nt][r2] + bv;
                Hcw[(size_t)nd*HID + col] = accC[nt][r2];
            }
        }
    }
    #undef NBF
}

// ---- final: dx(L=3) + vel = (x + dx - x0) - mean ----
__global__ void k_final(const float* __restrict__ xw, const float* __restrict__ xs,
                        const float* __restrict__ scalg, float* __restrict__ out)
{
    __shared__ float xstB[68], dxB[68], vb[68], mv3[3];
    const int b = blockIdx.x, t = threadIdx.x;
    if (t < 66) xstB[t] = xw[b*66 + t];
    if (t < 68) dxB[t] = 0.f;
    __syncthreads();
    for (int e = t; e < NEDGE; e += 256) {
        int a = e / NDEG, r = e - a*NDEG;
        int bb = r + (r >= a ? 1 : 0);
        float d0 = xstB[a*3+0] - xstB[bb*3+0];
        float d1 = xstB[a*3+1] - xstB[bb*3+1];
        float d2 = xstB[a*3+2] - xstB[bb*3+2];
        float inv = rsqrtf(d0*d0 + d1*d1 + d2*d2 + 1e-8f);
        float sc = scalg[(size_t)b*464 + e] * inv;
        atomicAdd(&dxB[a*3+0], d0*sc);
        atomicAdd(&dxB[a*3+1], d1*sc);
        atomicAdd(&dxB[a*3+2], d2*sc);
    }
    __syncthreads();
    if (t < 66) vb[t] = xstB[t] + dxB[t] - xs[b*66 + t];
    __syncthreads();
    if (t < 3) {
        float s = 0.f;
        #pragma unroll
        for (int p = 0; p < NPART; ++p) s += vb[p*3 + t];
        mv3[t] = s / (float)NPART;
    }
    __syncthreads();
    if (t < 66) out[b*66 + t] = vb[t] - mv3[t % 3];
}

extern "C" void kernel_launch(void* const* d_in, const int* in_sizes, int n_in,
                              void* d_out, int out_size, void* d_ws, size_t ws_size,
                              hipStream_t stream) {
    const float* t_in     = (const float*)d_in[0];
    const float* xs       = (const float*)d_in[1];
    const float* h_init   = (const float*)d_in[2];
    const float* emb_w    = (const float*)d_in[3];
    const float* emb_b    = (const float*)d_in[4];
    const float* edge_w1  = (const float*)d_in[7];
    const float* edge_b1  = (const float*)d_in[8];
    const float* edge_w2  = (const float*)d_in[9];
    const float* edge_b2  = (const float*)d_in[10];
    const float* node_w1  = (const float*)d_in[11];
    const float* node_b1  = (const float*)d_in[12];
    const float* node_w2  = (const float*)d_in[13];
    const float* node_b2  = (const float*)d_in[14];
    const float* coord_w1 = (const float*)d_in[15];
    const float* coord_b1 = (const float*)d_in[16];
    const float* coord_w2 = (const float*)d_in[17];
    float* outp = (float*)d_out;

    const int NB = in_sizes[0];
    const int NT = NB * NPART;
    float* xw      = (float*)d_ws;                 // NT*3
    float* hw      = xw   + (size_t)NT*3;          // NT*64
    float* Hrw     = hw   + (size_t)NT*HID;
    float* Hcw     = Hrw  + (size_t)NT*HID;
    float* aggpart = Hcw  + (size_t)NT*HID;        // NB*29*128
    float* scalg   = aggpart + (size_t)NB*NSTRIPB*128;  // NB*464
    float* eavg    = scalg + (size_t)NB*464;            // NB*464
    unsigned* wfrag = (unsigned*)(eavg + (size_t)NB*464);   // 8*512*4 u32
    unsigned* nfrag = wfrag + (size_t)8*512*4;              // 3*40*64*4 u32

    const int npairs = NB * NPAIRB;
    const int gA = (npairs + 3) / 4;
    const int gI = (NT + 3) / 4;
    const int nstripN = (NT + 15) / 16;
    const int gN = (nstripN + 3) / 4;
    const int gD = (NB + 3) / 4;

    prep_wfrag<<<8, 64, 0, stream>>>(edge_w2, coord_w1, wfrag);
    prep_nfrag<<<12, 64, 0, stream>>>(node_w1, node_w2, edge_w1, nfrag);
    k_eav<<<NB, 256, 0, stream>>>(xs, eavg);
    k_init<<<gI, 256, 0, stream>>>(t_in, xs, h_init, emb_w, emb_b,
                                   edge_w1, edge_b1, xw, hw, Hrw, Hcw, NT);
    for (int L = 0; L < NLAYERS; ++L) {
        k_edgeA<<<gA, 256, 0, stream>>>(
            edge_w1 + L*130*HID + 128*HID,
            edge_b2 + L*HID, coord_b1 + L*HID, coord_w2 + L*HID,
            wfrag, eavg, xw, Hrw, Hcw, aggpart, scalg, npairs, L);
        if (L < NLAYERS - 1) {
            k_dxnode<<<gD + gN, 256, 0, stream>>>(
                scalg, xw, NB, gD,
                nfrag + (size_t)L*40*64*4,
                node_b1 + L*HID, node_b2 + L*HID, edge_b1 + (L+1)*HID,
                aggpart, hw, Hrw, Hcw, NT, nstripN);
        }
    }
    k_final<<<NB, 256, 0, stream>>>(xw, xs, scalg, outp);
}

// Round 19
// 354.068 us; speedup vs baseline: 1.1502x; 1.1502x over previous
//
#include <hip/hip_runtime.h>
#include <hip/hip_fp16.h>

#define NPART 22
#define NDEG  21
#define NEDGE 462
#define HID   64
#define NLAYERS 4
#define NSTRIPB 29      // 16-edge strips per batch
#define MW2S  72        // u16 row stride of wave-private m tile

typedef _Float16 f16x8 __attribute__((ext_vector_type(8)));
typedef __attribute__((ext_vector_type(4))) float f32x4;
typedef __attribute__((ext_vector_type(4))) unsigned int u32x4;

__device__ __forceinline__ float silu_f(float v) {
    return __fdividef(v, 1.0f + __expf(-v));
}
__device__ __forceinline__ unsigned short hfu(float v) {
    return __half_as_ushort(__float2half(v));
}

// ---- edge-weight B-fragments: W2 / Wc1 per layer (f16) ----
__global__ void prep_wfrag(const float* __restrict__ edge_w2,
                           const float* __restrict__ coord_w1,
                           unsigned* __restrict__ wfrag)
{
    const int m = blockIdx.x;      // 0..7: L*2 + {0:W2, 1:Wc1}
    const int l = threadIdx.x;
    const int L = m >> 1;
    const float* W = (m & 1) ? (coord_w1 + L*HID*HID) : (edge_w2 + L*HID*HID);
    const int kg = l >> 4, j0 = l & 15;
    u32x4* ws4 = (u32x4*)wfrag;
    #pragma unroll
    for (int nt = 0; nt < 4; ++nt) {
        #pragma unroll
        for (int c = 0; c < 2; ++c) {
            u32x4 p;
            #pragma unroll
            for (int pi = 0; pi < 4; ++pi) {
                int k = c*32 + kg*8 + 2*pi;
                float v0 = W[k*HID + nt*16 + j0];
                float v1 = W[(k+1)*HID + nt*16 + j0];
                p[pi] = (unsigned)hfu(v0) | ((unsigned)hfu(v1) << 16);
            }
            ws4[m*512 + (nt*2 + c)*64 + l] = p;
        }
    }
}

// ---- node-weight B-fragments: wn1(K=128), wn2, we1r, we1c (f16) ----
__global__ void prep_nfrag(const float* __restrict__ node_w1,
                           const float* __restrict__ node_w2,
                           const float* __restrict__ edge_w1,
                           unsigned* __restrict__ nfrag)
{
    const int b = blockIdx.x;            // 0..11: L = b>>2, mat = b&3
    const int L = b >> 2, mat = b & 3;
    const int l = threadIdx.x;
    const int kg = l >> 4, j0 = l & 15;
    u32x4* nf = (u32x4*)nfrag + (size_t)L*40*64;
    const float* W; int nc, base;
    if      (mat == 0) { W = node_w1 + L*2*HID*HID;            nc = 4; base = 0;  }
    else if (mat == 1) { W = node_w2 + L*HID*HID;              nc = 2; base = 16; }
    else if (mat == 2) { W = edge_w1 + (L+1)*130*HID;          nc = 2; base = 24; }
    else               { W = edge_w1 + (L+1)*130*HID + 64*HID; nc = 2; base = 32; }
    for (int nt = 0; nt < 4; ++nt) {
        for (int c = 0; c < nc; ++c) {
            u32x4 p;
            #pragma unroll
            for (int pi = 0; pi < 4; ++pi) {
                int k = c*32 + kg*8 + 2*pi;
                float v0 = W[k*HID + nt*16 + j0];
                float v1 = W[(k+1)*HID + nt*16 + j0];
                p[pi] = (unsigned)hfu(v0) | ((unsigned)hfu(v1) << 16);
            }
            nf[(size_t)(base + nt*nc + c)*64 + l] = p;
        }
    }
}

// ---- init (blocks < gI): h embed + layer-0 Hr/Hc; (blocks >= gI): eav table ----
__global__ __launch_bounds__(256, 4)
void k_init(const float* __restrict__ t_in, const float* __restrict__ xs,
            const float* __restrict__ h_init,
            const float* __restrict__ emb_w, const float* __restrict__ emb_b,
            const float* __restrict__ edge_w1, const float* __restrict__ edge_b1,
            float* __restrict__ xw, float* __restrict__ hw,
            float* __restrict__ Hrw, float* __restrict__ Hcw,
            float* __restrict__ eavg, int NT, int gI)
{
    __shared__ __align__(16) float hbuf[4][68];
    __shared__ float xsh[68];
    const int w = threadIdx.x >> 6, l = threadIdx.x & 63;

    if (blockIdx.x >= (unsigned)gI) {
        // ---- eav part: one batch per block ----
        const int b = blockIdx.x - gI;
        const int t = threadIdx.x;
        if (t < 66) xsh[t] = xs[b*66 + t];
        __syncthreads();
        for (int e = t; e < NEDGE; e += 256) {
            int a = e / NDEG, r = e - a*NDEG;
            int bb = r + (r >= a ? 1 : 0);
            float d0 = xsh[a*3+0] - xsh[bb*3+0];
            float d1 = xsh[a*3+1] - xsh[bb*3+1];
            float d2 = xsh[a*3+2] - xsh[bb*3+2];
            eavg[(size_t)b*464 + e] = d0*d0 + d1*d1 + d2*d2;
        }
        return;
    }

    const int n = blockIdx.x*4 + w;
    if (n >= NT) return;
    const int bidx = n / NPART, p = n - bidx*NPART;
    float hv = emb_b[l] + t_in[bidx]*emb_w[8*HID + l];
    #pragma unroll
    for (int k = 0; k < 8; ++k) hv += h_init[p*8 + k]*emb_w[k*HID + l];
    hw[(size_t)n*HID + l] = hv;
    hbuf[w][l] = hv;
    float accr = edge_b1[l], accc = 0.f;
    #pragma unroll 4
    for (int k = 0; k < HID; ++k) {
        float hk = hbuf[w][k];
        accr += hk*edge_w1[k*HID + l];
        accc += hk*edge_w1[(HID + k)*HID + l];
    }
    Hrw[(size_t)n*HID + l] = accr;
    Hcw[(size_t)n*HID + l] = accc;
    if (l < 3) xw[n*3 + l] = xs[n*3 + l];
}

// ---- phase A: ONE 16-edge strip per wave (R17 regime); f16 MFMA ----
__global__ __launch_bounds__(256, 4)
void k_edgeA(const float* __restrict__ edge_w1v,   // vrad base; vea = +64
             const float* __restrict__ edge_b2L,
             const float* __restrict__ coord_b1L,
             const float* __restrict__ coord_w2L,
             const unsigned* __restrict__ wfrag,
             const float* __restrict__ eavg,
             const float* __restrict__ xw,
             const float* __restrict__ Hrw,
             const float* __restrict__ Hcw,
             float* __restrict__ aggpart,
             float* __restrict__ scalg,
             int nstrips, int Lmat)
{
    __shared__ __align__(16) unsigned short mwall[4][16*MW2S];
    __shared__ __align__(16) float xst[4][68];

    const int tid = threadIdx.x, l = tid & 63, w = tid >> 6;
    const int kg = l >> 4, j0 = l & 15;

    const int sid = blockIdx.x*4 + w;
    if (sid >= nstrips) return;
    const int batch = sid / NSTRIPB, s = sid - batch*NSTRIPB;
    const int e0 = s*16;
    const int ecnt = (NEDGE - e0 < 16) ? (NEDGE - e0) : 16;
    const int n0 = e0 / NDEG;

    {   // wave-private current-x staging (x0 plane replaced by eavg table)
        const int base = batch*66;
        xst[w][l] = xw[base + ((l < 66) ? l : 0)];
        if (l < 2) xst[w][64 + l] = xw[base + 64 + l];
    }

    int eg = e0 + j0; if (eg >= NEDGE) eg = NEDGE - 1;
    const int a  = eg / NDEG;
    const int r  = eg - a*NDEG;
    const int bb = r + (r >= a ? 1 : 0);
    float d0 = xst[w][a*3+0] - xst[w][bb*3+0];
    float d1 = xst[w][a*3+1] - xst[w][bb*3+1];
    float d2 = xst[w][a*3+2] - xst[w][bb*3+2];
    float rad = d0*d0 + d1*d1 + d2*d2;
    float eav = eavg[(size_t)batch*464 + eg];

    // B-fragment loads (L2-hot, f16)
    const u32x4* ws4 = (const u32x4*)wfrag;
    const u32x4* wb1 = ws4 + (size_t)(Lmat*2    )*512 + l;
    const u32x4* wb2 = ws4 + (size_t)(Lmat*2 + 1)*512 + l;
    f16x8 BW1[4][2];
    #pragma unroll
    for (int nt = 0; nt < 4; ++nt) {
        BW1[nt][0] = __builtin_bit_cast(f16x8, wb1[(nt*2 + 0)*64]);
        BW1[nt][1] = __builtin_bit_cast(f16x8, wb1[(nt*2 + 1)*64]);
    }
    float bv[4], cb[4], cwv[4];
    #pragma unroll
    for (int nt = 0; nt < 4; ++nt) {
        bv[nt]  = edge_b2L[nt*16 + j0];
        cb[nt]  = coord_b1L[nt*16 + j0];
        cwv[nt] = coord_w2L[nt*16 + j0];
    }

    // m1 A-fragments (f16, straight build)
    f16x8 A1[2];
    {
        const float* hrp = Hrw + (size_t)(batch*NPART + a)*HID;
        const float* hcp = Hcw + (size_t)(batch*NPART + bb)*HID;
        #pragma unroll
        for (int c = 0; c < 2; ++c) {
            const int k0 = c*32 + kg*8;
            float4 ra = *(const float4*)(hrp + k0);
            float4 rb = *(const float4*)(hrp + k0 + 4);
            float4 ca = *(const float4*)(hcp + k0);
            float4 cb4 = *(const float4*)(hcp + k0 + 4);
            float4 va = *(const float4*)(edge_w1v + k0);
            float4 vb = *(const float4*)(edge_w1v + k0 + 4);
            float4 ua = *(const float4*)(edge_w1v + 64 + k0);
            float4 ub = *(const float4*)(edge_w1v + 64 + k0 + 4);
            f16x8 A;
            A[0] = (_Float16)silu_f(ra.x + ca.x + rad*va.x + eav*ua.x);
            A[1] = (_Float16)silu_f(ra.y + ca.y + rad*va.y + eav*ua.y);
            A[2] = (_Float16)silu_f(ra.z + ca.z + rad*va.z + eav*ua.z);
            A[3] = (_Float16)silu_f(ra.w + ca.w + rad*va.w + eav*ua.w);
            A[4] = (_Float16)silu_f(rb.x + cb4.x + rad*vb.x + eav*ub.x);
            A[5] = (_Float16)silu_f(rb.y + cb4.y + rad*vb.y + eav*ub.y);
            A[6] = (_Float16)silu_f(rb.z + cb4.z + rad*vb.z + eav*ub.z);
            A[7] = (_Float16)silu_f(rb.w + cb4.w + rad*vb.w + eav*ub.w);
            A1[c] = A;
        }
    }

    // GEMM1: m = m1 @ W2
    f32x4 acc[4];
    #pragma unroll
    for (int nt = 0; nt < 4; ++nt) {
        f32x4 z = {0.f, 0.f, 0.f, 0.f};
        z = __builtin_amdgcn_mfma_f32_16x16x32_f16(A1[0], BW1[nt][0], z, 0, 0, 0);
        z = __builtin_amdgcn_mfma_f32_16x16x32_f16(A1[1], BW1[nt][1], z, 0, 0, 0);
        acc[nt] = z;
    }

    // GEMM2 B-fragment loads (latency hides under epilogue 1)
    f16x8 B2[4][2];
    #pragma unroll
    for (int nt = 0; nt < 4; ++nt) {
        B2[nt][0] = __builtin_bit_cast(f16x8, wb2[(nt*2 + 0)*64]);
        B2[nt][1] = __builtin_bit_cast(f16x8, wb2[(nt*2 + 1)*64]);
    }

    // epilogue 1: silu+bias (emask-folded), f16 tile store, partials pS/pT
    int sel[4], emask[4];
    #pragma unroll
    for (int r2 = 0; r2 < 4; ++r2) {
        int e2 = kg*4 + r2;
        int eg2 = e0 + e2; if (eg2 >= NEDGE) eg2 = NEDGE - 1;
        sel[r2] = (eg2 / NDEG == n0);
        emask[r2] = (e2 < ecnt);
    }
    unsigned short* mw = mwall[w];
    float pS[4] = {0.f,0.f,0.f,0.f}, pT[4] = {0.f,0.f,0.f,0.f};
    #pragma unroll
    for (int nt = 0; nt < 4; ++nt) {
        int j = nt*16 + j0;
        #pragma unroll
        for (int r2 = 0; r2 < 4; ++r2) {
            float mv = emask[r2] ? silu_f(acc[nt][r2] + bv[nt]) : 0.f;
            mw[(kg*4 + r2)*MW2S + j] = hfu(mv);
            pT[nt] += mv;
            pS[nt] += sel[r2] ? mv : 0.f;
        }
    }
    #pragma unroll
    for (int nt = 0; nt < 4; ++nt) {
        pS[nt] += __shfl_xor(pS[nt], 16);
        pS[nt] += __shfl_xor(pS[nt], 32);
        pT[nt] += __shfl_xor(pT[nt], 16);
        pT[nt] += __shfl_xor(pT[nt], 32);
    }
    {
        float* apb = aggpart + (size_t)(batch*NSTRIPB + s)*128;
        if (kg == 0) {
            #pragma unroll
            for (int nt = 0; nt < 4; ++nt) apb[nt*16 + j0] = pS[nt];
        } else if (kg == 1) {
            #pragma unroll
            for (int nt = 0; nt < 4; ++nt) apb[64 + nt*16 + j0] = pT[nt] - pS[nt];
        }
    }

    // GEMM2 A-fragments: direct b128 reads from f16 tile
    f16x8 A2[2];
    {
        const unsigned short* arp = mw + j0*MW2S;
        A2[0] = *(const f16x8*)(arp + kg*8);
        A2[1] = *(const f16x8*)(arp + 32 + kg*8);
    }

    // GEMM2: c1 = m @ Wc1
    f32x4 acc2[4];
    #pragma unroll
    for (int nt = 0; nt < 4; ++nt) {
        f32x4 z = {0.f, 0.f, 0.f, 0.f};
        z = __builtin_amdgcn_mfma_f32_16x16x32_f16(A2[0], B2[nt][0], z, 0, 0, 0);
        z = __builtin_amdgcn_mfma_f32_16x16x32_f16(A2[1], B2[nt][1], z, 0, 0, 0);
        acc2[nt] = z;
    }

    // epilogue 2: scal reduce over j0 lanes, store per edge
    float pr[4] = {0.f,0.f,0.f,0.f};
    #pragma unroll
    for (int nt = 0; nt < 4; ++nt) {
        #pragma unroll
        for (int r2 = 0; r2 < 4; ++r2)
            pr[r2] += silu_f(acc2[nt][r2] + cb[nt]) * cwv[nt];
    }
    #pragma unroll
    for (int off = 8; off > 0; off >>= 1) {
        #pragma unroll
        for (int r2 = 0; r2 < 4; ++r2)
            pr[r2] += __shfl_xor(pr[r2], off);
    }
    if (j0 == 0) {
        #pragma unroll
        for (int r2 = 0; r2 < 4; ++r2) {
            int e2 = kg*4 + r2;
            if (e2 < ecnt) scalg[(size_t)batch*464 + e0 + e2] = pr[r2];
        }
    }
}

// ---- fused: dx+x update (blocks < gD) | node MFMA phase (blocks >= gD) ----
__global__ __launch_bounds__(256, 2)
void k_dxnode(const float* __restrict__ scalg, float* __restrict__ xw, int NB, int gD,
              const unsigned* __restrict__ nfragL,
              const float* __restrict__ nb1p, const float* __restrict__ nb2p,
              const float* __restrict__ eb1p,
              const float* __restrict__ aggpart,
              float* __restrict__ hw,
              float* __restrict__ Hrw, float* __restrict__ Hcw,
              int NT, int nstripN)
{
    __shared__ __align__(16) float hT[4][16][68];
    __shared__ __align__(16) float hnT[4][16][68];
    __shared__ float xstd[4][68], dxd[4][68];
    const int tid = threadIdx.x, l = tid & 63, w = tid >> 6;
    const int kg = l >> 4, j0 = l & 15;

    if (blockIdx.x < (unsigned)gD) {
        const int batch = blockIdx.x*4 + w;
        if (batch >= NB) return;
        xstd[w][l] = xw[batch*66 + ((l < 66) ? l : 0)];
        if (l < 2) xstd[w][64 + l] = xw[batch*66 + 64 + l];
        dxd[w][l] = 0.f;
        if (l < 4) dxd[w][64 + l] = 0.f;
        for (int e = l; e < NEDGE; e += 64) {
            int a = e / NDEG, r = e - a*NDEG;
            int bb = r + (r >= a ? 1 : 0);
            float d0 = xstd[w][a*3+0] - xstd[w][bb*3+0];
            float d1 = xstd[w][a*3+1] - xstd[w][bb*3+1];
            float d2 = xstd[w][a*3+2] - xstd[w][bb*3+2];
            float inv = rsqrtf(d0*d0 + d1*d1 + d2*d2 + 1e-8f);
            float sc = scalg[(size_t)batch*464 + e] * inv;
            atomicAdd(&dxd[w][a*3+0], d0*sc);
            atomicAdd(&dxd[w][a*3+1], d1*sc);
            atomicAdd(&dxd[w][a*3+2], d2*sc);
        }
        xw[batch*66 + ((l < 66) ? l : 0)] = xstd[w][l] + dxd[w][l];
        if (l < 2) xw[batch*66 + 64 + l] = xstd[w][64 + l] + dxd[w][64 + l];
        return;
    }

    const int sid = (blockIdx.x - gD)*4 + w;
    if (sid >= nstripN) return;

    {
        int row = l >> 2, cc = (l & 3) << 4;
        int nd = sid*16 + row; if (nd >= NT) nd = NT - 1;
        const float* src = hw + (size_t)nd*HID + cc;
        *(float4*)&hT[w][row][cc]      = *(const float4*)(src);
        *(float4*)&hT[w][row][cc + 4]  = *(const float4*)(src + 4);
        *(float4*)&hT[w][row][cc + 8]  = *(const float4*)(src + 8);
        *(float4*)&hT[w][row][cc + 12] = *(const float4*)(src + 12);
    }

    const int ndl  = sid*16 + j0;
    const int ndc  = (ndl < NT) ? ndl : NT - 1;
    const int bidx = ndc / NPART, p = ndc - bidx*NPART;

    f16x8 A1[4];
    #pragma unroll
    for (int c = 0; c < 2; ++c) {
        f16x8 A;
        #pragma unroll
        for (int i = 0; i < 8; ++i) A[i] = (_Float16)hT[w][j0][c*32 + kg*8 + i];
        A1[c] = A;
    }
    {
        const int smin = (NDEG*p) >> 4;
        const int smax = (NDEG*p + 20) >> 4;
        #pragma unroll
        for (int c = 2; c < 4; ++c) {
            const int k0a = (c - 2)*32 + kg*8;
            float tv[8] = {0.f,0.f,0.f,0.f,0.f,0.f,0.f,0.f};
            for (int s = smin; s <= smax; ++s) {
                int slot = (p == (s*16)/NDEG) ? 0 : 1;
                const float* ap = aggpart + (size_t)(bidx*NSTRIPB + s)*128 + slot*64 + k0a;
                float4 qa = *(const float4*)ap;
                float4 qb = *(const float4*)(ap + 4);
                tv[0] += qa.x; tv[1] += qa.y; tv[2] += qa.z; tv[3] += qa.w;
                tv[4] += qb.x; tv[5] += qb.y; tv[6] += qb.z; tv[7] += qb.w;
            }
            f16x8 A;
            #pragma unroll
            for (int i = 0; i < 8; ++i) A[i] = (_Float16)tv[i];
            A1[c] = A;
        }
    }

    const u32x4* nf = (const u32x4*)nfragL;
    #define NBF(idx) __builtin_bit_cast(f16x8, nf[(size_t)(idx)*64 + l])

    f32x4 acc1[4];
    #pragma unroll
    for (int nt = 0; nt < 4; ++nt) {
        f32x4 z = {0.f, 0.f, 0.f, 0.f};
        #pragma unroll
        for (int c = 0; c < 4; ++c)
            z = __builtin_amdgcn_mfma_f32_16x16x32_f16(A1[c], NBF(nt*4 + c), z, 0, 0, 0);
        acc1[nt] = z;
    }
    #pragma unroll
    for (int nt = 0; nt < 4; ++nt) {
        float bv = nb1p[nt*16 + j0];
        #pragma unroll
        for (int r2 = 0; r2 < 4; ++r2)
            hnT[w][kg*4 + r2][nt*16 + j0] = silu_f(acc1[nt][r2] + bv);
    }

    f16x8 A2[2];
    #pragma unroll
    for (int c = 0; c < 2; ++c) {
        f16x8 A;
        #pragma unroll
        for (int i = 0; i < 8; ++i) A[i] = (_Float16)hnT[w][j0][c*32 + kg*8 + i];
        A2[c] = A;
    }
    f32x4 acc2[4];
    #pragma unroll
    for (int nt = 0; nt < 4; ++nt) {
        f32x4 z = {0.f, 0.f, 0.f, 0.f};
        #pragma unroll
        for (int c = 0; c < 2; ++c)
            z = __builtin_amdgcn_mfma_f32_16x16x32_f16(A2[c], NBF(16 + nt*2 + c), z, 0, 0, 0);
        acc2[nt] = z;
    }
    #pragma unroll
    for (int nt = 0; nt < 4; ++nt) {
        float bv = nb2p[nt*16 + j0];
        #pragma unroll
        for (int r2 = 0; r2 < 4; ++r2) {
            int row = kg*4 + r2, col = nt*16 + j0;
            float hv = hT[w][row][col] + acc2[nt][r2] + bv;
            hnT[w][row][col] = hv;
            int nd = sid*16 + row;
            if (nd < NT) hw[(size_t)nd*HID + col] = hv;
        }
    }

    f16x8 A3[2];
    #pragma unroll
    for (int c = 0; c < 2; ++c) {
        f16x8 A;
        #pragma unroll
        for (int i = 0; i < 8; ++i) A[i] = (_Float16)hnT[w][j0][c*32 + kg*8 + i];
        A3[c] = A;
    }
    f32x4 accR[4], accC[4];
    #pragma unroll
    for (int nt = 0; nt < 4; ++nt) {
        f32x4 zr = {0.f,0.f,0.f,0.f}, zc = {0.f,0.f,0.f,0.f};
        #pragma unroll
        for (int c = 0; c < 2; ++c) {
            zr = __builtin_amdgcn_mfma_f32_16x16x32_f16(A3[c], NBF(24 + nt*2 + c), zr, 0, 0, 0);
            zc = __builtin_amdgcn_mfma_f32_16x16x32_f16(A3[c], NBF(32 + nt*2 + c), zc, 0, 0, 0);
        }
        accR[nt] = zr; accC[nt] = zc;
    }
    #pragma unroll
    for (int nt = 0; nt < 4; ++nt) {
        float bv = eb1p[nt*16 + j0];
        #pragma unroll
        for (int r2 = 0; r2 < 4; ++r2) {
            int row = kg*4 + r2, col = nt*16 + j0;
            int nd = sid*16 + row;
            if (nd < NT) {
                Hrw[(size_t)nd*HID + col] = accR[nt][r2] + bv;
                Hcw[(size_t)nd*HID + col] = accC[nt][r2];
            }
        }
    }
    #undef NBF
}

// ---- final: dx(L=3) + vel = (x + dx - x0) - mean ----
__global__ void k_final(const float* __restrict__ xw, const float* __restrict__ xs,
                        const float* __restrict__ scalg, float* __restrict__ out)
{
    __shared__ float xstB[68], dxB[68], vb[68], mv3[3];
    const int b = blockIdx.x, t = threadIdx.x;
    if (t < 66) xstB[t] = xw[b*66 + t];
    if (t < 68) dxB[t] = 0.f;
    __syncthreads();
    for (int e = t; e < NEDGE; e += 256) {
        int a = e / NDEG, r = e - a*NDEG;
        int bb = r + (r >= a ? 1 : 0);
        float d0 = xstB[a*3+0] - xstB[bb*3+0];
        float d1 = xstB[a*3+1] - xstB[bb*3+1];
        float d2 = xstB[a*3+2] - xstB[bb*3+2];
        float inv = rsqrtf(d0*d0 + d1*d1 + d2*d2 + 1e-8f);
        float sc = scalg[(size_t)b*464 + e] * inv;
        atomicAdd(&dxB[a*3+0], d0*sc);
        atomicAdd(&dxB[a*3+1], d1*sc);
        atomicAdd(&dxB[a*3+2], d2*sc);
    }
    __syncthreads();
    if (t < 66) vb[t] = xstB[t] + dxB[t] - xs[b*66 + t];
    __syncthreads();
    if (t < 3) {
        float s = 0.f;
        #pragma unroll
        for (int p = 0; p < NPART; ++p) s += vb[p*3 + t];
        mv3[t] = s / (float)NPART;
    }
    __syncthreads();
    if (t < 66) out[b*66 + t] = vb[t] - mv3[t % 3];
}

extern "C" void kernel_launch(void* const* d_in, const int* in_sizes, int n_in,
                              void* d_out, int out_size, void* d_ws, size_t ws_size,
                              hipStream_t stream) {
    const float* t_in     = (const float*)d_in[0];
    const float* xs       = (const float*)d_in[1];
    const float* h_init   = (const float*)d_in[2];
    const float* emb_w    = (const float*)d_in[3];
    const float* emb_b    = (const float*)d_in[4];
    const float* edge_w1  = (const float*)d_in[7];
    const float* edge_b1  = (const float*)d_in[8];
    const float* edge_w2  = (const float*)d_in[9];
    const float* edge_b2  = (const float*)d_in[10];
    const float* node_w1  = (const float*)d_in[11];
    const float* node_b1  = (const float*)d_in[12];
    const float* node_w2  = (const float*)d_in[13];
    const float* node_b2  = (const float*)d_in[14];
    const float* coord_w1 = (const float*)d_in[15];
    const float* coord_b1 = (const float*)d_in[16];
    const float* coord_w2 = (const float*)d_in[17];
    float* outp = (float*)d_out;

    const int NB = in_sizes[0];
    const int NT = NB * NPART;
    float* xw      = (float*)d_ws;                 // NT*3
    float* hw      = xw   + (size_t)NT*3;          // NT*64
    float* Hrw     = hw   + (size_t)NT*HID;
    float* Hcw     = Hrw  + (size_t)NT*HID;
    float* aggpart = Hcw  + (size_t)NT*HID;        // NB*29*128
    float* scalg   = aggpart + (size_t)NB*NSTRIPB*128;  // NB*464
    float* eavg    = scalg + (size_t)NB*464;            // NB*464
    unsigned* wfrag = (unsigned*)(eavg + (size_t)NB*464);   // 8*512*4 u32
    unsigned* nfrag = wfrag + (size_t)8*512*4;              // 3*40*64*4 u32

    const int nstrips = NB * NSTRIPB;
    const int gA = (nstrips + 3) / 4;
    const int gI = (NT + 3) / 4;
    const int nstripN = (NT + 15) / 16;
    const int gN = (nstripN + 3) / 4;
    const int gD = (NB + 3) / 4;

    prep_wfrag<<<8, 64, 0, stream>>>(edge_w2, coord_w1, wfrag);
    prep_nfrag<<<12, 64, 0, stream>>>(node_w1, node_w2, edge_w1, nfrag);
    k_init<<<gI + NB, 256, 0, stream>>>(t_in, xs, h_init, emb_w, emb_b,
                                        edge_w1, edge_b1, xw, hw, Hrw, Hcw,
                                        eavg, NT, gI);
    for (int L = 0; L < NLAYERS; ++L) {
        k_edgeA<<<gA, 256, 0, stream>>>(
            edge_w1 + L*130*HID + 128*HID,
            edge_b2 + L*HID, coord_b1 + L*HID, coord_w2 + L*HID,
            wfrag, eavg, xw, Hrw, Hcw, aggpart, scalg, nstrips, L);
        if (L < NLAYERS - 1) {
            k_dxnode<<<gD + gN, 256, 0, stream>>>(
                scalg, xw, NB, gD,
                nfrag + (size_t)L*40*64*4,
                node_b1 + L*HID, node_b2 + L*HID, edge_b1 + (L+1)*HID,
                aggpart, hw, Hrw, Hcw, NT, nstripN);
        }
    }
    k_final<<<NB, 256, 0, stream>>>(xw, xs, scalg, outp);
}

// Round 20
// 348.222 us; speedup vs baseline: 1.1695x; 1.0168x over previous
//
#include <hip/hip_runtime.h>
#include <hip/hip_fp16.h>

#define NPART 22
#define NDEG  21
#define NEDGE 462
#define HID   64
#define NLAYERS 4
#define NSTRIPB 29      // 16-edge strips per batch
#define MW2S  72        // u16 row stride of wave-private m tile

typedef _Float16 f16x8 __attribute__((ext_vector_type(8)));
typedef __attribute__((ext_vector_type(4))) float f32x4;
typedef __attribute__((ext_vector_type(4))) unsigned int u32x4;

__device__ __forceinline__ float silu_f(float v) {
    return __fdividef(v, 1.0f + __expf(-v));
}
__device__ __forceinline__ unsigned short hfu(float v) {
    return __half_as_ushort(__float2half(v));
}

// ---- edge-weight B-fragments: W2 / Wc1 per layer (f16) ----
__global__ void prep_wfrag(const float* __restrict__ edge_w2,
                           const float* __restrict__ coord_w1,
                           unsigned* __restrict__ wfrag)
{
    const int m = blockIdx.x;      // 0..7: L*2 + {0:W2, 1:Wc1}
    const int l = threadIdx.x;
    const int L = m >> 1;
    const float* W = (m & 1) ? (coord_w1 + L*HID*HID) : (edge_w2 + L*HID*HID);
    const int kg = l >> 4, j0 = l & 15;
    u32x4* ws4 = (u32x4*)wfrag;
    #pragma unroll
    for (int nt = 0; nt < 4; ++nt) {
        #pragma unroll
        for (int c = 0; c < 2; ++c) {
            u32x4 p;
            #pragma unroll
            for (int pi = 0; pi < 4; ++pi) {
                int k = c*32 + kg*8 + 2*pi;
                float v0 = W[k*HID + nt*16 + j0];
                float v1 = W[(k+1)*HID + nt*16 + j0];
                p[pi] = (unsigned)hfu(v0) | ((unsigned)hfu(v1) << 16);
            }
            ws4[m*512 + (nt*2 + c)*64 + l] = p;
        }
    }
}

// ---- node-weight B-fragments: wn1(K=128), wn2, we1r, we1c (f16) ----
__global__ void prep_nfrag(const float* __restrict__ node_w1,
                           const float* __restrict__ node_w2,
                           const float* __restrict__ edge_w1,
                           unsigned* __restrict__ nfrag)
{
    const int b = blockIdx.x;            // 0..11: L = b>>2, mat = b&3
    const int L = b >> 2, mat = b & 3;
    const int l = threadIdx.x;
    const int kg = l >> 4, j0 = l & 15;
    u32x4* nf = (u32x4*)nfrag + (size_t)L*40*64;
    const float* W; int nc, base;
    if      (mat == 0) { W = node_w1 + L*2*HID*HID;            nc = 4; base = 0;  }
    else if (mat == 1) { W = node_w2 + L*HID*HID;              nc = 2; base = 16; }
    else if (mat == 2) { W = edge_w1 + (L+1)*130*HID;          nc = 2; base = 24; }
    else               { W = edge_w1 + (L+1)*130*HID + 64*HID; nc = 2; base = 32; }
    for (int nt = 0; nt < 4; ++nt) {
        for (int c = 0; c < nc; ++c) {
            u32x4 p;
            #pragma unroll
            for (int pi = 0; pi < 4; ++pi) {
                int k = c*32 + kg*8 + 2*pi;
                float v0 = W[k*HID + nt*16 + j0];
                float v1 = W[(k+1)*HID + nt*16 + j0];
                p[pi] = (unsigned)hfu(v0) | ((unsigned)hfu(v1) << 16);
            }
            nf[(size_t)(base + nt*nc + c)*64 + l] = p;
        }
    }
}

// ---- init (blocks < gI): h embed + layer-0 Hr/Hc; (blocks >= gI): eav table ----
__global__ __launch_bounds__(256, 4)
void k_init(const float* __restrict__ t_in, const float* __restrict__ xs,
            const float* __restrict__ h_init,
            const float* __restrict__ emb_w, const float* __restrict__ emb_b,
            const float* __restrict__ edge_w1, const float* __restrict__ edge_b1,
            float* __restrict__ xw, float* __restrict__ hw,
            float* __restrict__ Hrw, float* __restrict__ Hcw,
            float* __restrict__ eavg, int NT, int gI)
{
    __shared__ __align__(16) float hbuf[4][68];
    __shared__ float xsh[68];
    const int w = threadIdx.x >> 6, l = threadIdx.x & 63;

    if (blockIdx.x >= (unsigned)gI) {
        const int b = blockIdx.x - gI;
        const int t = threadIdx.x;
        if (t < 66) xsh[t] = xs[b*66 + t];
        __syncthreads();
        for (int e = t; e < NEDGE; e += 256) {
            int a = e / NDEG, r = e - a*NDEG;
            int bb = r + (r >= a ? 1 : 0);
            float d0 = xsh[a*3+0] - xsh[bb*3+0];
            float d1 = xsh[a*3+1] - xsh[bb*3+1];
            float d2 = xsh[a*3+2] - xsh[bb*3+2];
            eavg[(size_t)b*464 + e] = d0*d0 + d1*d1 + d2*d2;
        }
        return;
    }

    const int n = blockIdx.x*4 + w;
    if (n >= NT) return;
    const int bidx = n / NPART, p = n - bidx*NPART;
    float hv = emb_b[l] + t_in[bidx]*emb_w[8*HID + l];
    #pragma unroll
    for (int k = 0; k < 8; ++k) hv += h_init[p*8 + k]*emb_w[k*HID + l];
    hw[(size_t)n*HID + l] = hv;
    hbuf[w][l] = hv;
    float accr = edge_b1[l], accc = 0.f;
    #pragma unroll 4
    for (int k = 0; k < HID; ++k) {
        float hk = hbuf[w][k];
        accr += hk*edge_w1[k*HID + l];
        accc += hk*edge_w1[(HID + k)*HID + l];
    }
    Hrw[(size_t)n*HID + l] = accr;
    Hcw[(size_t)n*HID + l] = accc;
    if (l < 3) xw[n*3 + l] = xs[n*3 + l];
}

// ---- phase A: ONE 16-edge strip per wave; f16 MFMA; 6 blocks/CU residency ----
__global__ __launch_bounds__(256, 6)
void k_edgeA(const float* __restrict__ edge_w1v,   // vrad base; vea = +64
             const float* __restrict__ edge_b2L,
             const float* __restrict__ coord_b1L,
             const float* __restrict__ coord_w2L,
             const unsigned* __restrict__ wfrag,
             const float* __restrict__ eavg,
             const float* __restrict__ xw,
             const float* __restrict__ Hrw,
             const float* __restrict__ Hcw,
             float* __restrict__ aggpart,
             float* __restrict__ scalg,
             int nstrips, int Lmat)
{
    __shared__ __align__(16) unsigned short mwall[4][16*MW2S];
    __shared__ __align__(16) float xst[4][68];

    const int tid = threadIdx.x, l = tid & 63, w = tid >> 6;
    const int kg = l >> 4, j0 = l & 15;

    const int sid = blockIdx.x*4 + w;
    if (sid >= nstrips) return;
    const int batch = sid / NSTRIPB, s = sid - batch*NSTRIPB;
    const int e0 = s*16;
    const int ecnt = (NEDGE - e0 < 16) ? (NEDGE - e0) : 16;
    const int n0 = e0 / NDEG;

    {   // wave-private current-x staging
        const int base = batch*66;
        xst[w][l] = xw[base + ((l < 66) ? l : 0)];
        if (l < 2) xst[w][64 + l] = xw[base + 64 + l];
    }

    int eg = e0 + j0; if (eg >= NEDGE) eg = NEDGE - 1;
    const int a  = eg / NDEG;
    const int r  = eg - a*NDEG;
    const int bb = r + (r >= a ? 1 : 0);
    float d0 = xst[w][a*3+0] - xst[w][bb*3+0];
    float d1 = xst[w][a*3+1] - xst[w][bb*3+1];
    float d2 = xst[w][a*3+2] - xst[w][bb*3+2];
    float rad = d0*d0 + d1*d1 + d2*d2;
    float eav = eavg[(size_t)batch*464 + eg];

    // B-fragment loads (L2-hot, f16)
    const u32x4* ws4 = (const u32x4*)wfrag;
    const u32x4* wb1 = ws4 + (size_t)(Lmat*2    )*512 + l;
    const u32x4* wb2 = ws4 + (size_t)(Lmat*2 + 1)*512 + l;
    f16x8 BW1[4][2];
    #pragma unroll
    for (int nt = 0; nt < 4; ++nt) {
        BW1[nt][0] = __builtin_bit_cast(f16x8, wb1[(nt*2 + 0)*64]);
        BW1[nt][1] = __builtin_bit_cast(f16x8, wb1[(nt*2 + 1)*64]);
    }
    float bv[4], cb[4], cwv[4];
    #pragma unroll
    for (int nt = 0; nt < 4; ++nt) {
        bv[nt]  = edge_b2L[nt*16 + j0];
        cb[nt]  = coord_b1L[nt*16 + j0];
        cwv[nt] = coord_w2L[nt*16 + j0];
    }

    // m1 A-fragments (f16, straight build)
    f16x8 A1[2];
    {
        const float* hrp = Hrw + (size_t)(batch*NPART + a)*HID;
        const float* hcp = Hcw + (size_t)(batch*NPART + bb)*HID;
        #pragma unroll
        for (int c = 0; c < 2; ++c) {
            const int k0 = c*32 + kg*8;
            float4 ra = *(const float4*)(hrp + k0);
            float4 rb = *(const float4*)(hrp + k0 + 4);
            float4 ca = *(const float4*)(hcp + k0);
            float4 cb4 = *(const float4*)(hcp + k0 + 4);
            float4 va = *(const float4*)(edge_w1v + k0);
            float4 vb = *(const float4*)(edge_w1v + k0 + 4);
            float4 ua = *(const float4*)(edge_w1v + 64 + k0);
            float4 ub = *(const float4*)(edge_w1v + 64 + k0 + 4);
            f16x8 A;
            A[0] = (_Float16)silu_f(ra.x + ca.x + rad*va.x + eav*ua.x);
            A[1] = (_Float16)silu_f(ra.y + ca.y + rad*va.y + eav*ua.y);
            A[2] = (_Float16)silu_f(ra.z + ca.z + rad*va.z + eav*ua.z);
            A[3] = (_Float16)silu_f(ra.w + ca.w + rad*va.w + eav*ua.w);
            A[4] = (_Float16)silu_f(rb.x + cb4.x + rad*vb.x + eav*ub.x);
            A[5] = (_Float16)silu_f(rb.y + cb4.y + rad*vb.y + eav*ub.y);
            A[6] = (_Float16)silu_f(rb.z + cb4.z + rad*vb.z + eav*ub.z);
            A[7] = (_Float16)silu_f(rb.w + cb4.w + rad*vb.w + eav*ub.w);
            A1[c] = A;
        }
    }

    // GEMM1: m = m1 @ W2
    f32x4 acc[4];
    #pragma unroll
    for (int nt = 0; nt < 4; ++nt) {
        f32x4 z = {0.f, 0.f, 0.f, 0.f};
        z = __builtin_amdgcn_mfma_f32_16x16x32_f16(A1[0], BW1[nt][0], z, 0, 0, 0);
        z = __builtin_amdgcn_mfma_f32_16x16x32_f16(A1[1], BW1[nt][1], z, 0, 0, 0);
        acc[nt] = z;
    }

    // GEMM2 B-fragment loads (latency hides under epilogue 1)
    f16x8 B2[4][2];
    #pragma unroll
    for (int nt = 0; nt < 4; ++nt) {
        B2[nt][0] = __builtin_bit_cast(f16x8, wb2[(nt*2 + 0)*64]);
        B2[nt][1] = __builtin_bit_cast(f16x8, wb2[(nt*2 + 1)*64]);
    }

    // epilogue 1: silu+bias (emask-folded), f16 tile store, partials pS/pT
    int sel[4], emask[4];
    #pragma unroll
    for (int r2 = 0; r2 < 4; ++r2) {
        int e2 = kg*4 + r2;
        int eg2 = e0 + e2; if (eg2 >= NEDGE) eg2 = NEDGE - 1;
        sel[r2] = (eg2 / NDEG == n0);
        emask[r2] = (e2 < ecnt);
    }
    unsigned short* mw = mwall[w];
    float pS[4] = {0.f,0.f,0.f,0.f}, pT[4] = {0.f,0.f,0.f,0.f};
    #pragma unroll
    for (int nt = 0; nt < 4; ++nt) {
        int j = nt*16 + j0;
        #pragma unroll
        for (int r2 = 0; r2 < 4; ++r2) {
            float mv = emask[r2] ? silu_f(acc[nt][r2] + bv[nt]) : 0.f;
            mw[(kg*4 + r2)*MW2S + j] = hfu(mv);
            pT[nt] += mv;
            pS[nt] += sel[r2] ? mv : 0.f;
        }
    }
    #pragma unroll
    for (int nt = 0; nt < 4; ++nt) {
        pS[nt] += __shfl_xor(pS[nt], 16);
        pS[nt] += __shfl_xor(pS[nt], 32);
        pT[nt] += __shfl_xor(pT[nt], 16);
        pT[nt] += __shfl_xor(pT[nt], 32);
    }
    {
        float* apb = aggpart + (size_t)(batch*NSTRIPB + s)*128;
        if (kg == 0) {
            #pragma unroll
            for (int nt = 0; nt < 4; ++nt) apb[nt*16 + j0] = pS[nt];
        } else if (kg == 1) {
            #pragma unroll
            for (int nt = 0; nt < 4; ++nt) apb[64 + nt*16 + j0] = pT[nt] - pS[nt];
        }
    }

    // GEMM2 A-fragments: direct b128 reads from f16 tile
    f16x8 A2[2];
    {
        const unsigned short* arp = mw + j0*MW2S;
        A2[0] = *(const f16x8*)(arp + kg*8);
        A2[1] = *(const f16x8*)(arp + 32 + kg*8);
    }

    // GEMM2: c1 = m @ Wc1
    f32x4 acc2[4];
    #pragma unroll
    for (int nt = 0; nt < 4; ++nt) {
        f32x4 z = {0.f, 0.f, 0.f, 0.f};
        z = __builtin_amdgcn_mfma_f32_16x16x32_f16(A2[0], B2[nt][0], z, 0, 0, 0);
        z = __builtin_amdgcn_mfma_f32_16x16x32_f16(A2[1], B2[nt][1], z, 0, 0, 0);
        acc2[nt] = z;
    }

    // epilogue 2: scal reduce over j0 lanes, store per edge
    float pr[4] = {0.f,0.f,0.f,0.f};
    #pragma unroll
    for (int nt = 0; nt < 4; ++nt) {
        #pragma unroll
        for (int r2 = 0; r2 < 4; ++r2)
            pr[r2] += silu_f(acc2[nt][r2] + cb[nt]) * cwv[nt];
    }
    #pragma unroll
    for (int off = 8; off > 0; off >>= 1) {
        #pragma unroll
        for (int r2 = 0; r2 < 4; ++r2)
            pr[r2] += __shfl_xor(pr[r2], off);
    }
    if (j0 == 0) {
        #pragma unroll
        for (int r2 = 0; r2 < 4; ++r2) {
            int e2 = kg*4 + r2;
            if (e2 < ecnt) scalg[(size_t)batch*464 + e0 + e2] = pr[r2];
        }
    }
}

// ---- fused: dx+x update (blocks < gD) | node MFMA phase (blocks >= gD) ----
__global__ __launch_bounds__(256, 2)
void k_dxnode(const float* __restrict__ scalg, float* __restrict__ xw, int NB, int gD,
              const unsigned* __restrict__ nfragL,
              const float* __restrict__ nb1p, const float* __restrict__ nb2p,
              const float* __restrict__ eb1p,
              const float* __restrict__ aggpart,
              float* __restrict__ hw,
              float* __restrict__ Hrw, float* __restrict__ Hcw,
              int NT, int nstripN)
{
    __shared__ __align__(16) float hT[4][16][68];
    __shared__ __align__(16) float hnT[4][16][68];
    __shared__ float xstd[4][68], dxd[4][68];
    const int tid = threadIdx.x, l = tid & 63, w = tid >> 6;
    const int kg = l >> 4, j0 = l & 15;

    if (blockIdx.x < (unsigned)gD) {
        const int batch = blockIdx.x*4 + w;
        if (batch >= NB) return;
        xstd[w][l] = xw[batch*66 + ((l < 66) ? l : 0)];
        if (l < 2) xstd[w][64 + l] = xw[batch*66 + 64 + l];
        dxd[w][l] = 0.f;
        if (l < 4) dxd[w][64 + l] = 0.f;
        for (int e = l; e < NEDGE; e += 64) {
            int a = e / NDEG, r = e - a*NDEG;
            int bb = r + (r >= a ? 1 : 0);
            float d0 = xstd[w][a*3+0] - xstd[w][bb*3+0];
            float d1 = xstd[w][a*3+1] - xstd[w][bb*3+1];
            float d2 = xstd[w][a*3+2] - xstd[w][bb*3+2];
            float inv = rsqrtf(d0*d0 + d1*d1 + d2*d2 + 1e-8f);
            float sc = scalg[(size_t)batch*464 + e] * inv;
            atomicAdd(&dxd[w][a*3+0], d0*sc);
            atomicAdd(&dxd[w][a*3+1], d1*sc);
            atomicAdd(&dxd[w][a*3+2], d2*sc);
        }
        xw[batch*66 + ((l < 66) ? l : 0)] = xstd[w][l] + dxd[w][l];
        if (l < 2) xw[batch*66 + 64 + l] = xstd[w][64 + l] + dxd[w][64 + l];
        return;
    }

    const int sid = (blockIdx.x - gD)*4 + w;
    if (sid >= nstripN) return;

    {
        int row = l >> 2, cc = (l & 3) << 4;
        int nd = sid*16 + row; if (nd >= NT) nd = NT - 1;
        const float* src = hw + (size_t)nd*HID + cc;
        *(float4*)&hT[w][row][cc]      = *(const float4*)(src);
        *(float4*)&hT[w][row][cc + 4]  = *(const float4*)(src + 4);
        *(float4*)&hT[w][row][cc + 8]  = *(const float4*)(src + 8);
        *(float4*)&hT[w][row][cc + 12] = *(const float4*)(src + 12);
    }

    const int ndl  = sid*16 + j0;
    const int ndc  = (ndl < NT) ? ndl : NT - 1;
    const int bidx = ndc / NPART, p = ndc - bidx*NPART;

    f16x8 A1[4];
    #pragma unroll
    for (int c = 0; c < 2; ++c) {
        f16x8 A;
        #pragma unroll
        for (int i = 0; i < 8; ++i) A[i] = (_Float16)hT[w][j0][c*32 + kg*8 + i];
        A1[c] = A;
    }
    {
        const int smin = (NDEG*p) >> 4;
        const int smax = (NDEG*p + 20) >> 4;
        #pragma unroll
        for (int c = 2; c < 4; ++c) {
            const int k0a = (c - 2)*32 + kg*8;
            float tv[8] = {0.f,0.f,0.f,0.f,0.f,0.f,0.f,0.f};
            for (int s = smin; s <= smax; ++s) {
                int slot = (p == (s*16)/NDEG) ? 0 : 1;
                const float* ap = aggpart + (size_t)(bidx*NSTRIPB + s)*128 + slot*64 + k0a;
                float4 qa = *(const float4*)ap;
                float4 qb = *(const float4*)(ap + 4);
                tv[0] += qa.x; tv[1] += qa.y; tv[2] += qa.z; tv[3] += qa.w;
                tv[4] += qb.x; tv[5] += qb.y; tv[6] += qb.z; tv[7] += qb.w;
            }
            f16x8 A;
            #pragma unroll
            for (int i = 0; i < 8; ++i) A[i] = (_Float16)tv[i];
            A1[c] = A;
        }
    }

    const u32x4* nf = (const u32x4*)nfragL;
    #define NBF(idx) __builtin_bit_cast(f16x8, nf[(size_t)(idx)*64 + l])

    f32x4 acc1[4];
    #pragma unroll
    for (int nt = 0; nt < 4; ++nt) {
        f32x4 z = {0.f, 0.f, 0.f, 0.f};
        #pragma unroll
        for (int c = 0; c < 4; ++c)
            z = __builtin_amdgcn_mfma_f32_16x16x32_f16(A1[c], NBF(nt*4 + c), z, 0, 0, 0);
        acc1[nt] = z;
    }
    #pragma unroll
    for (int nt = 0; nt < 4; ++nt) {
        float bv = nb1p[nt*16 + j0];
        #pragma unroll
        for (int r2 = 0; r2 < 4; ++r2)
            hnT[w][kg*4 + r2][nt*16 + j0] = silu_f(acc1[nt][r2] + bv);
    }

    f16x8 A2[2];
    #pragma unroll
    for (int c = 0; c < 2; ++c) {
        f16x8 A;
        #pragma unroll
        for (int i = 0; i < 8; ++i) A[i] = (_Float16)hnT[w][j0][c*32 + kg*8 + i];
        A2[c] = A;
    }
    f32x4 acc2[4];
    #pragma unroll
    for (int nt = 0; nt < 4; ++nt) {
        f32x4 z = {0.f, 0.f, 0.f, 0.f};
        #pragma unroll
        for (int c = 0; c < 2; ++c)
            z = __builtin_amdgcn_mfma_f32_16x16x32_f16(A2[c], NBF(16 + nt*2 + c), z, 0, 0, 0);
        acc2[nt] = z;
    }
    #pragma unroll
    for (int nt = 0; nt < 4; ++nt) {
        float bv = nb2p[nt*16 + j0];
        #pragma unroll
        for (int r2 = 0; r2 < 4; ++r2) {
            int row = kg*4 + r2, col = nt*16 + j0;
            float hv = hT[w][row][col] + acc2[nt][r2] + bv;
            hnT[w][row][col] = hv;
            int nd = sid*16 + row;
            if (nd < NT) hw[(size_t)nd*HID + col] = hv;
        }
    }

    f16x8 A3[2];
    #pragma unroll
    for (int c = 0; c < 2; ++c) {
        f16x8 A;
        #pragma unroll
        for (int i = 0; i < 8; ++i) A[i] = (_Float16)hnT[w][j0][c*32 + kg*8 + i];
        A3[c] = A;
    }
    f32x4 accR[4], accC[4];
    #pragma unroll
    for (int nt = 0; nt < 4; ++nt) {
        f32x4 zr = {0.f,0.f,0.f,0.f}, zc = {0.f,0.f,0.f,0.f};
        #pragma unroll
        for (int c = 0; c < 2; ++c) {
            zr = __builtin_amdgcn_mfma_f32_16x16x32_f16(A3[c], NBF(24 + nt*2 + c), zr, 0, 0, 0);
            zc = __builtin_amdgcn_mfma_f32_16x16x32_f16(A3[c], NBF(32 + nt*2 + c), zc, 0, 0, 0);
        }
        accR[nt] = zr; accC[nt] = zc;
    }
    #pragma unroll
    for (int nt = 0; nt < 4; ++nt) {
        float bv = eb1p[nt*16 + j0];
        #pragma unroll
        for (int r2 = 0; r2 < 4; ++r2) {
            int row = kg*4 + r2, col = nt*16 + j0;
            int nd = sid*16 + row;
            if (nd < NT) {
                Hrw[(size_t)nd*HID + col] = accR[nt][r2] + bv;
                Hcw[(size_t)nd*HID + col] = accC[nt][r2];
            }
        }
    }
    #undef NBF
}

// ---- final: dx(L=3) + vel = (x + dx - x0) - mean ----
__global__ void k_final(const float* __restrict__ xw, const float* __restrict__ xs,
                        const float* __restrict__ scalg, float* __restrict__ out)
{
    __shared__ float xstB[68], dxB[68], vb[68], mv3[3];
    const int b = blockIdx.x, t = threadIdx.x;
    if (t < 66) xstB[t] = xw[b*66 + t];
    if (t < 68) dxB[t] = 0.f;
    __syncthreads();
    for (int e = t; e < NEDGE; e += 256) {
        int a = e / NDEG, r = e - a*NDEG;
        int bb = r + (r >= a ? 1 : 0);
        float d0 = xstB[a*3+0] - xstB[bb*3+0];
        float d1 = xstB[a*3+1] - xstB[bb*3+1];
        float d2 = xstB[a*3+2] - xstB[bb*3+2];
        float inv = rsqrtf(d0*d0 + d1*d1 + d2*d2 + 1e-8f);
        float sc = scalg[(size_t)b*464 + e] * inv;
        atomicAdd(&dxB[a*3+0], d0*sc);
        atomicAdd(&dxB[a*3+1], d1*sc);
        atomicAdd(&dxB[a*3+2], d2*sc);
    }
    __syncthreads();
    if (t < 66) vb[t] = xstB[t] + dxB[t] - xs[b*66 + t];
    __syncthreads();
    if (t < 3) {
        float s = 0.f;
        #pragma unroll
        for (int p = 0; p < NPART; ++p) s += vb[p*3 + t];
        mv3[t] = s / (float)NPART;
    }
    __syncthreads();
    if (t < 66) out[b*66 + t] = vb[t] - mv3[t % 3];
}

extern "C" void kernel_launch(void* const* d_in, const int* in_sizes, int n_in,
                              void* d_out, int out_size, void* d_ws, size_t ws_size,
                              hipStream_t stream) {
    const float* t_in     = (const float*)d_in[0];
    const float* xs       = (const float*)d_in[1];
    const float* h_init   = (const float*)d_in[2];
    const float* emb_w    = (const float*)d_in[3];
    const float* emb_b    = (const float*)d_in[4];
    const float* edge_w1  = (const float*)d_in[7];
    const float* edge_b1  = (const float*)d_in[8];
    const float* edge_w2  = (const float*)d_in[9];
    const float* edge_b2  = (const float*)d_in[10];
    const float* node_w1  = (const float*)d_in[11];
    const float* node_b1  = (const float*)d_in[12];
    const float* node_w2  = (const float*)d_in[13];
    const float* node_b2  = (const float*)d_in[14];
    const float* coord_w1 = (const float*)d_in[15];
    const float* coord_b1 = (const float*)d_in[16];
    const float* coord_w2 = (const float*)d_in[17];
    float* outp = (float*)d_out;

    const int NB = in_sizes[0];
    const int NT = NB * NPART;
    float* xw      = (float*)d_ws;                 // NT*3
    float* hw      = xw   + (size_t)NT*3;          // NT*64
    float* Hrw     = hw   + (size_t)NT*HID;
    float* Hcw     = Hrw  + (size_t)NT*HID;
    float* aggpart = Hcw  + (size_t)NT*HID;        // NB*29*128
    float* scalg   = aggpart + (size_t)NB*NSTRIPB*128;  // NB*464
    float* eavg    = scalg + (size_t)NB*464;            // NB*464
    unsigned* wfrag = (unsigned*)(eavg + (size_t)NB*464);   // 8*512*4 u32
    unsigned* nfrag = wfrag + (size_t)8*512*4;              // 3*40*64*4 u32

    const int nstrips = NB * NSTRIPB;
    const int gA = (nstrips + 3) / 4;
    const int gI = (NT + 3) / 4;
    const int nstripN = (NT + 15) / 16;
    const int gN = (nstripN + 3) / 4;
    const int gD = (NB + 3) / 4;

    prep_wfrag<<<8, 64, 0, stream>>>(edge_w2, coord_w1, wfrag);
    prep_nfrag<<<12, 64, 0, stream>>>(node_w1, node_w2, edge_w1, nfrag);
    k_init<<<gI + NB, 256, 0, stream>>>(t_in, xs, h_init, emb_w, emb_b,
                                        edge_w1, edge_b1, xw, hw, Hrw, Hcw,
                                        eavg, NT, gI);
    for (int L = 0; L < NLAYERS; ++L) {
        k_edgeA<<<gA, 256, 0, stream>>>(
            edge_w1 + L*130*HID + 128*HID,
            edge_b2 + L*HID, coord_b1 + L*HID, coord_w2 + L*HID,
            wfrag, eavg, xw, Hrw, Hcw, aggpart, scalg, nstrips, L);
        if (L < NLAYERS - 1) {
            k_dxnode<<<gD + gN, 256, 0, stream>>>(
                scalg, xw, NB, gD,
                nfrag + (size_t)L*40*64*4,
                node_b1 + L*HID, node_b2 + L*HID, edge_b1 + (L+1)*HID,
                aggpart, hw, Hrw, Hcw, NT, nstripN);
        }
    }
    k_final<<<NB, 256, 0, stream>>>(xw, xs, scalg, outp);
}